// Round 6
// baseline (435.164 us; speedup 1.0000x reference)
//
#include <hip/hip_runtime.h>
#include <hip/hip_bf16.h>
#include <cstdint>

// Problem constants: N=4096 tokens, D=1024, H=2048, E=8, TOP_K=2
#define N_TOK 4096
#define DIM   1024
#define HID   2048
#define NE    8

typedef __bf16 bf16x8 __attribute__((ext_vector_type(8)));
typedef __bf16 bf16x4 __attribute__((ext_vector_type(4)));
typedef float  f32x4  __attribute__((ext_vector_type(4)));

// Async global->LDS DMA, 16B/lane. LDS dest = wave-uniform base + lane*16.
__device__ __forceinline__ void gload16(const void* g, void* l) {
    __builtin_amdgcn_global_load_lds(
        (const __attribute__((address_space(1))) void*)g,
        (__attribute__((address_space(3))) void*)l, 16, 0, 0);
}

// ---------------------------------------------------------------------------
// Both weight transposes in one launch. lin<16384: W1 [D][H]->[H][D];
// else W2 [H][D]->[D][H]. 32x32 tiles via LDS.
// ---------------------------------------------------------------------------
__global__ void transpose_cvt_all(const float* __restrict__ W1, const float* __restrict__ W2,
                                  __bf16* __restrict__ w1t, __bf16* __restrict__ w2t) {
    int lin = blockIdx.x;
    const float* src; __bf16* dst; int R, C, rx, cy;
    if (lin < 16384) {
        const int e = lin >> 11, rem = lin & 2047;
        rx = rem >> 6; cy = rem & 63;           // R/32=32, C/32=64
        R = DIM; C = HID;
        src = W1 + (size_t)e * DIM * HID; dst = w1t + (size_t)e * DIM * HID;
    } else {
        lin -= 16384;
        const int e = lin >> 11, rem = lin & 2047;
        rx = rem >> 5; cy = rem & 31;           // R/32=64, C/32=32
        R = HID; C = DIM;
        src = W2 + (size_t)e * DIM * HID; dst = w2t + (size_t)e * DIM * HID;
    }
    __shared__ float t[32][33];
    const int r0 = rx * 32, c0 = cy * 32;
    const int tr = threadIdx.x >> 3;
    const int tc = (threadIdx.x & 7) * 4;
    float4 v = *(const float4*)&src[(size_t)(r0 + tr) * C + c0 + tc];
    t[tr][tc + 0] = v.x; t[tr][tc + 1] = v.y; t[tr][tc + 2] = v.z; t[tr][tc + 3] = v.w;
    __syncthreads();
    bf16x4 o;
    o[0] = (__bf16)t[tc + 0][tr];
    o[1] = (__bf16)t[tc + 1][tr];
    o[2] = (__bf16)t[tc + 2][tr];
    o[3] = (__bf16)t[tc + 3][tr];
    *(bf16x4*)&dst[(size_t)(c0 + tr) * R + r0 + tc] = o;
}

// ---------------------------------------------------------------------------
// Gating + x->bf16 conversion fused. One wave per token. No atomics.
// ---------------------------------------------------------------------------
__global__ void gate_kernel(const float* __restrict__ x, const float* __restrict__ gW,
                            const float* __restrict__ gb, int* __restrict__ top_idx,
                            float* __restrict__ top_gate, __bf16* __restrict__ xb) {
    const int tokn = blockIdx.x * 4 + (threadIdx.x >> 6);
    const int lane = threadIdx.x & 63;
    const float4* xr = (const float4*)(x + (size_t)tokn * DIM);
    __bf16* xbr = xb + (size_t)tokn * DIM;
    float acc[NE] = {};
#pragma unroll
    for (int i = 0; i < 4; i++) {
        const int v4 = i * 64 + lane;            // float4 index 0..255
        const float4 xv = xr[v4];
        bf16x4 xc = { (__bf16)xv.x, (__bf16)xv.y, (__bf16)xv.z, (__bf16)xv.w };
        *(bf16x4*)&xbr[v4 * 4] = xc;
        const float* wb = &gW[v4 * 4 * NE];      // 4 rows x 8 experts
        const float xs[4] = { xv.x, xv.y, xv.z, xv.w };
#pragma unroll
        for (int j = 0; j < 4; j++) {
            const float4 wa = *(const float4*)&wb[j * NE];
            const float4 wc = *(const float4*)&wb[j * NE + 4];
            acc[0] += xs[j] * wa.x; acc[1] += xs[j] * wa.y;
            acc[2] += xs[j] * wa.z; acc[3] += xs[j] * wa.w;
            acc[4] += xs[j] * wc.x; acc[5] += xs[j] * wc.y;
            acc[6] += xs[j] * wc.z; acc[7] += xs[j] * wc.w;
        }
    }
#pragma unroll
    for (int e = 0; e < NE; e++)
#pragma unroll
        for (int s = 32; s > 0; s >>= 1)
            acc[e] += __shfl_down(acc[e], s, 64);
    if (lane == 0) {
        float lg[NE], p[NE];
        float mx = -1e30f;
#pragma unroll
        for (int e = 0; e < NE; e++) { lg[e] = acc[e] + gb[e]; mx = fmaxf(mx, lg[e]); }
        float s = 0.f;
#pragma unroll
        for (int e = 0; e < NE; e++) { p[e] = __expf(lg[e] - mx); s += p[e]; }
        const float inv = 1.f / s;
#pragma unroll
        for (int e = 0; e < NE; e++) p[e] *= inv;
        int i0 = 0; float p0 = p[0];
#pragma unroll
        for (int e = 1; e < NE; e++) if (p[e] > p0) { p0 = p[e]; i0 = e; }
        int i1 = -1; float p1 = -1.f;
#pragma unroll
        for (int e = 0; e < NE; e++) if (e != i0 && p[e] > p1) { p1 = p[e]; i1 = e; }
        top_idx[tokn * 2] = i0;  top_idx[tokn * 2 + 1] = i1;
        top_gate[tokn * 2] = p0; top_gate[tokn * 2 + 1] = p1;
    }
}

// LDS histogram -> 8 global atomics per block (16 blocks => 128 total).
__global__ void count_kernel(const int* __restrict__ top_idx, int* __restrict__ cnt) {
    __shared__ int hist[NE];
    if (threadIdx.x < NE) hist[threadIdx.x] = 0;
    __syncthreads();
    const int n = blockIdx.x * 256 + threadIdx.x;
    atomicAdd(&hist[top_idx[n * 2]], 1);
    atomicAdd(&hist[top_idx[n * 2 + 1]], 1);
    __syncthreads();
    if (threadIdx.x < NE) atomicAdd(&cnt[threadIdx.x], hist[threadIdx.x]);
}

// Row assignment: inline 8-wide prefix scan + LDS ranks + 8 global atomics/block.
__global__ void build_kernel(const int* __restrict__ top_idx, const int* __restrict__ cnt,
                             int* __restrict__ run, int* __restrict__ row_token,
                             int* __restrict__ tok_row) {
    __shared__ int soffs[NE];
    __shared__ int lrun[NE];
    __shared__ int base[NE];
    if (threadIdx.x == 0) {
        int s = 0;
        for (int e = 0; e < NE; e++) { soffs[e] = s; s += cnt[e]; }
    }
    if (threadIdx.x < NE) lrun[threadIdx.x] = 0;
    __syncthreads();
    const int n = blockIdx.x * 256 + threadIdx.x;
    const int e0 = top_idx[n * 2], e1 = top_idx[n * 2 + 1];
    const int p0 = atomicAdd(&lrun[e0], 1);
    const int p1 = atomicAdd(&lrun[e1], 1);
    __syncthreads();
    if (threadIdx.x < NE) base[threadIdx.x] = atomicAdd(&run[threadIdx.x], lrun[threadIdx.x]);
    __syncthreads();
    const int r0 = soffs[e0] + base[e0] + p0;
    const int r1 = soffs[e1] + base[e1] + p1;
    row_token[r0] = n; tok_row[n * 2] = r0;
    row_token[r1] = n; tok_row[n * 2 + 1] = r1;
}

// ---------------------------------------------------------------------------
// Grouped GEMM1: h[r] = relu(x[tok(r)] @ W1t[e] + b1[e]), bf16 out.
// 128x128 tile, BK=128: A staged in LDS (32KB, XOR-swizzled, 8 DMA/wave/step),
// B fragments loaded DIRECTLY global->VGPR (L1/L2-resident weights, no barrier
// dependency). 64 MFMA per wave per barrier (4x the old ratio).
// XCD-aware 1-D grid: lin = e + 8*(n0t*32 + mt)  =>  xcd ~= lin%8 = e.
// ---------------------------------------------------------------------------
__global__ __launch_bounds__(256, 2) void gemm1_kernel(
    const __bf16* __restrict__ xb, const __bf16* __restrict__ w1t,
    const float* __restrict__ b1, const int* __restrict__ cnt,
    const int* __restrict__ row_token, __bf16* __restrict__ h) {
    const int lin = blockIdx.x;
    const int e   = lin & 7;
    const int t   = lin >> 3;
    const int mt  = t & 31;
    const int n0  = (t >> 5) * 128;
    int off_e = 0;
    for (int i = 0; i < e; i++) off_e += cnt[i];
    const int ce = cnt[e];
    if (mt * 128 >= ce) return;

    __shared__ __bf16 lA[16384];   // 128 rows x 128 cols = 32KB, swizzled

    const int tid  = threadIdx.x;
    const int lane = tid & 63;
    const int wid  = tid >> 6;
    const int quad = lane >> 4;
    const int l16  = lane & 15;
    const int wm   = wid & 1;
    const int wn   = wid >> 1;

    // A staging: DMA g = wid*8+j covers rows 4g..4g+3; lane -> (lrow, chunk c).
    // Row r chunk q stored at slot c = q ^ (r&7)  (swizzle for conflict-free reads).
    const int lrow = lane >> 4;              // 0..3
    const int cc   = lane & 15;              // slot
    const __bf16* aros[8];
    char* ldsA[8];
#pragma unroll
    for (int j = 0; j < 8; j++) {
        const int g   = wid * 8 + j;
        const int row = g * 4 + lrow;                 // tile row 0..127
        const int q   = cc ^ (((j & 1) << 2) | lrow); // global 16B-chunk
        int gr = off_e + mt * 128 + row;
        gr = gr < 2 * N_TOK - 1 ? gr : 2 * N_TOK - 1;
        const int tok = row_token[gr] & (N_TOK - 1);
        aros[j] = xb + (size_t)tok * DIM + q * 8;
        ldsA[j] = (char*)lA + g * 1024;
    }

    // B fragment base pointers: lane (l16, quad) reads row n0+wn*64+ni*16+l16,
    // k-bytes quad*16 within each 32-elem chunk.
    const __bf16* bp[4];
#pragma unroll
    for (int ni = 0; ni < 4; ni++)
        bp[ni] = w1t + ((size_t)e * HID + n0 + wn * 64 + ni * 16 + l16) * DIM + quad * 8;

    f32x4 acc[4][4] = {};

    for (int kk = 0; kk < DIM; kk += 128) {
#pragma unroll
        for (int j = 0; j < 8; j++) gload16(aros[j] + kk, ldsA[j]);
        __syncthreads();
#pragma unroll
        for (int hh = 0; hh < 4; hh++) {
            bf16x8 bfr[4];
#pragma unroll
            for (int ni = 0; ni < 4; ni++)
                bfr[ni] = *(const bf16x8*)(bp[ni] + kk + hh * 32);
            const int sw = (((hh * 4 + quad) ^ (l16 & 7)) << 4);
            bf16x8 af[4];
#pragma unroll
            for (int mi = 0; mi < 4; mi++)
                af[mi] = *(const bf16x8*)((const char*)lA + (wm * 64 + mi * 16 + l16) * 256 + sw);
#pragma unroll
            for (int mi = 0; mi < 4; mi++)
#pragma unroll
                for (int ni = 0; ni < 4; ni++)
                    acc[mi][ni] = __builtin_amdgcn_mfma_f32_16x16x32_bf16(af[mi], bfr[ni], acc[mi][ni], 0, 0, 0);
        }
        __syncthreads();
    }

#pragma unroll
    for (int ni = 0; ni < 4; ni++) {
        const int col = n0 + wn * 64 + ni * 16 + l16;
        const float bias = b1[e * HID + col];
#pragma unroll
        for (int mi = 0; mi < 4; mi++) {
#pragma unroll
            for (int r = 0; r < 4; r++) {
                const int lr = wm * 64 + mi * 16 + quad * 4 + r;
                const int gm = mt * 128 + lr;
                if (gm < ce) {
                    float v = acc[mi][ni][r] + bias;
                    v = v > 0.f ? v : 0.f;
                    h[(size_t)(off_e + gm) * HID + col] = (__bf16)v;
                }
            }
        }
    }
}

// ---------------------------------------------------------------------------
// Grouped GEMM2: y[r] = h[r] @ W2t[e] + b2[e], fp32 out. Same structure.
// ---------------------------------------------------------------------------
__global__ __launch_bounds__(256, 2) void gemm2_kernel(
    const __bf16* __restrict__ h, const __bf16* __restrict__ w2t,
    const float* __restrict__ b2, const int* __restrict__ cnt,
    float* __restrict__ y) {
    const int lin = blockIdx.x;
    const int e   = lin & 7;
    const int t   = lin >> 3;
    const int mt  = t & 31;
    const int n0  = (t >> 5) * 128;
    int off_e = 0;
    for (int i = 0; i < e; i++) off_e += cnt[i];
    const int ce = cnt[e];
    if (mt * 128 >= ce) return;

    __shared__ __bf16 lA[16384];

    const int tid  = threadIdx.x;
    const int lane = tid & 63;
    const int wid  = tid >> 6;
    const int quad = lane >> 4;
    const int l16  = lane & 15;
    const int wm   = wid & 1;
    const int wn   = wid >> 1;

    const int lrow = lane >> 4;
    const int cc   = lane & 15;
    const __bf16* aros[8];
    char* ldsA[8];
#pragma unroll
    for (int j = 0; j < 8; j++) {
        const int g   = wid * 8 + j;
        const int row = g * 4 + lrow;
        const int q   = cc ^ (((j & 1) << 2) | lrow);
        int gr = off_e + mt * 128 + row;
        gr = gr < 2 * N_TOK - 1 ? gr : 2 * N_TOK - 1;   // clamp inside h buffer
        aros[j] = h + (size_t)gr * HID + q * 8;
        ldsA[j] = (char*)lA + g * 1024;
    }

    const __bf16* bp[4];
#pragma unroll
    for (int ni = 0; ni < 4; ni++)
        bp[ni] = w2t + ((size_t)e * DIM + n0 + wn * 64 + ni * 16 + l16) * HID + quad * 8;

    f32x4 acc[4][4] = {};

    for (int kk = 0; kk < HID; kk += 128) {
#pragma unroll
        for (int j = 0; j < 8; j++) gload16(aros[j] + kk, ldsA[j]);
        __syncthreads();
#pragma unroll
        for (int hh = 0; hh < 4; hh++) {
            bf16x8 bfr[4];
#pragma unroll
            for (int ni = 0; ni < 4; ni++)
                bfr[ni] = *(const bf16x8*)(bp[ni] + kk + hh * 32);
            const int sw = (((hh * 4 + quad) ^ (l16 & 7)) << 4);
            bf16x8 af[4];
#pragma unroll
            for (int mi = 0; mi < 4; mi++)
                af[mi] = *(const bf16x8*)((const char*)lA + (wm * 64 + mi * 16 + l16) * 256 + sw);
#pragma unroll
            for (int mi = 0; mi < 4; mi++)
#pragma unroll
                for (int ni = 0; ni < 4; ni++)
                    acc[mi][ni] = __builtin_amdgcn_mfma_f32_16x16x32_bf16(af[mi], bfr[ni], acc[mi][ni], 0, 0, 0);
        }
        __syncthreads();
    }

#pragma unroll
    for (int mi = 0; mi < 4; mi++) {
#pragma unroll
        for (int r = 0; r < 4; r++) {
            const int lr = wm * 64 + mi * 16 + quad * 4 + r;
            const int gm = mt * 128 + lr;
            if (gm < ce) {
#pragma unroll
                for (int ni = 0; ni < 4; ni++) {
                    const int col = n0 + wn * 64 + ni * 16 + l16;
                    y[(size_t)(off_e + gm) * DIM + col] = acc[mi][ni][r] + b2[e * DIM + col];
                }
            }
        }
    }
}

// out[n] = g0*y[r0] + g1*y[r1] — coalesced, one block per token row.
__global__ void combine_kernel(const float* __restrict__ y, const int* __restrict__ tok_row,
                               const float* __restrict__ top_gate, float* __restrict__ out) {
    const int n = blockIdx.x;
    const int d = threadIdx.x * 4;
    const int r0 = tok_row[n * 2], r1 = tok_row[n * 2 + 1];
    const float g0 = top_gate[n * 2], g1 = top_gate[n * 2 + 1];
    float4 a = *(const float4*)&y[(size_t)r0 * DIM + d];
    float4 b = *(const float4*)&y[(size_t)r1 * DIM + d];
    float4 o = { g0 * a.x + g1 * b.x, g0 * a.y + g1 * b.y,
                 g0 * a.z + g1 * b.z, g0 * a.w + g1 * b.w };
    *(float4*)&out[(size_t)n * DIM + d] = o;
}

// ---------------------------------------------------------------------------
extern "C" void kernel_launch(void* const* d_in, const int* in_sizes, int n_in,
                              void* d_out, int out_size, void* d_ws, size_t ws_size,
                              hipStream_t stream) {
    const float* x  = (const float*)d_in[0];
    const float* gW = (const float*)d_in[1];
    const float* gb = (const float*)d_in[2];
    const float* W1 = (const float*)d_in[3];
    const float* b1 = (const float*)d_in[4];
    const float* W2 = (const float*)d_in[5];
    const float* b2 = (const float*)d_in[6];
    float* out = (float*)d_out;

    char* ws = (char*)d_ws;
    // ws layout:
    //   [0, 8 MiB)    xb  : x bf16 [N][D]
    //   [8, 40 MiB)   w1t : W1^T bf16 [E][H][D]   (dead after gemm1)
    //   [8, 40 MiB)   y   : fp32 [2N][D]          (overlays w1t)
    //   [40, 72 MiB)  w2t : W2^T bf16 [E][D][H]
    //   [72, 104 MiB) h   : bf16 [2N][H]
    //   [104 MiB..)   routing metadata
    __bf16* xb   = (__bf16*)(ws);
    __bf16* w1t  = (__bf16*)(ws + ((size_t)8  << 20));
    float*  ybuf = (float*) (ws + ((size_t)8  << 20));
    __bf16* w2t  = (__bf16*)(ws + ((size_t)40 << 20));
    __bf16* hbuf = (__bf16*)(ws + ((size_t)72 << 20));
    char* tail   = ws + ((size_t)104 << 20);
    int*   row_token = (int*)(tail);
    int*   tok_row   = (int*)(tail + 32768);
    int*   top_idx   = (int*)(tail + 65536);
    float* top_gate  = (float*)(tail + 98304);
    int*   cnt       = (int*)(tail + 131072);
    int*   run       = cnt + 32;

    hipMemsetAsync(cnt, 0, 256, stream);

    gate_kernel<<<N_TOK / 4, 256, 0, stream>>>(x, gW, gb, top_idx, top_gate, xb);
    count_kernel<<<N_TOK / 256, 256, 0, stream>>>(top_idx, cnt);
    build_kernel<<<N_TOK / 256, 256, 0, stream>>>(top_idx, cnt, run, row_token, tok_row);
    transpose_cvt_all<<<32768, 256, 0, stream>>>(W1, W2, w1t, w2t);
    // XCD-aware 1-D grids: lin = e + 8*(n0t*32 + mt)
    gemm1_kernel<<<NE * 32 * (HID / 128), 256, 0, stream>>>(xb, w1t, b1, cnt, row_token, hbuf);
    gemm2_kernel<<<NE * 32 * (DIM / 128), 256, 0, stream>>>(hbuf, w2t, b2, cnt, ybuf);
    combine_kernel<<<N_TOK, 256, 0, stream>>>(ybuf, tok_row, top_gate, out);
}

// Round 7
// 337.919 us; speedup vs baseline: 1.2878x; 1.2878x over previous
//
#include <hip/hip_runtime.h>
#include <hip/hip_bf16.h>
#include <cstdint>

// Problem constants: N=4096 tokens, D=1024, H=2048, E=8, TOP_K=2
#define N_TOK 4096
#define DIM   1024
#define HID   2048
#define NE    8

typedef __bf16 bf16x8 __attribute__((ext_vector_type(8)));
typedef __bf16 bf16x4 __attribute__((ext_vector_type(4)));
typedef float  f32x4  __attribute__((ext_vector_type(4)));

// Async global->LDS DMA, 16B/lane. LDS dest = wave-uniform base + lane*16.
__device__ __forceinline__ void gload16(const void* g, void* l) {
    __builtin_amdgcn_global_load_lds(
        (const __attribute__((address_space(1))) void*)g,
        (__attribute__((address_space(3))) void*)l, 16, 0, 0);
}

// ---------------------------------------------------------------------------
// Both weight transposes in one launch. lin<16384: W1 [D][H]->[H][D];
// else W2 [H][D]->[D][H]. 32x32 tiles via LDS.
// ---------------------------------------------------------------------------
__global__ void transpose_cvt_all(const float* __restrict__ W1, const float* __restrict__ W2,
                                  __bf16* __restrict__ w1t, __bf16* __restrict__ w2t) {
    int lin = blockIdx.x;
    const float* src; __bf16* dst; int R, C, rx, cy;
    if (lin < 16384) {
        const int e = lin >> 11, rem = lin & 2047;
        rx = rem >> 6; cy = rem & 63;           // R/32=32, C/32=64
        R = DIM; C = HID;
        src = W1 + (size_t)e * DIM * HID; dst = w1t + (size_t)e * DIM * HID;
    } else {
        lin -= 16384;
        const int e = lin >> 11, rem = lin & 2047;
        rx = rem >> 5; cy = rem & 31;           // R/32=64, C/32=32
        R = HID; C = DIM;
        src = W2 + (size_t)e * DIM * HID; dst = w2t + (size_t)e * DIM * HID;
    }
    __shared__ float t[32][33];
    const int r0 = rx * 32, c0 = cy * 32;
    const int tr = threadIdx.x >> 3;
    const int tc = (threadIdx.x & 7) * 4;
    float4 v = *(const float4*)&src[(size_t)(r0 + tr) * C + c0 + tc];
    t[tr][tc + 0] = v.x; t[tr][tc + 1] = v.y; t[tr][tc + 2] = v.z; t[tr][tc + 3] = v.w;
    __syncthreads();
    bf16x4 o;
    o[0] = (__bf16)t[tc + 0][tr];
    o[1] = (__bf16)t[tc + 1][tr];
    o[2] = (__bf16)t[tc + 2][tr];
    o[3] = (__bf16)t[tc + 3][tr];
    *(bf16x4*)&dst[(size_t)(c0 + tr) * R + r0 + tc] = o;
}

// ---------------------------------------------------------------------------
// Gating + x->bf16 conversion fused. One wave per token. No atomics.
// ---------------------------------------------------------------------------
__global__ void gate_kernel(const float* __restrict__ x, const float* __restrict__ gW,
                            const float* __restrict__ gb, int* __restrict__ top_idx,
                            float* __restrict__ top_gate, __bf16* __restrict__ xb) {
    const int tokn = blockIdx.x * 4 + (threadIdx.x >> 6);
    const int lane = threadIdx.x & 63;
    const float4* xr = (const float4*)(x + (size_t)tokn * DIM);
    __bf16* xbr = xb + (size_t)tokn * DIM;
    float acc[NE] = {};
#pragma unroll
    for (int i = 0; i < 4; i++) {
        const int v4 = i * 64 + lane;            // float4 index 0..255
        const float4 xv = xr[v4];
        bf16x4 xc = { (__bf16)xv.x, (__bf16)xv.y, (__bf16)xv.z, (__bf16)xv.w };
        *(bf16x4*)&xbr[v4 * 4] = xc;
        const float* wb = &gW[v4 * 4 * NE];      // 4 rows x 8 experts
        const float xs[4] = { xv.x, xv.y, xv.z, xv.w };
#pragma unroll
        for (int j = 0; j < 4; j++) {
            const float4 wa = *(const float4*)&wb[j * NE];
            const float4 wc = *(const float4*)&wb[j * NE + 4];
            acc[0] += xs[j] * wa.x; acc[1] += xs[j] * wa.y;
            acc[2] += xs[j] * wa.z; acc[3] += xs[j] * wa.w;
            acc[4] += xs[j] * wc.x; acc[5] += xs[j] * wc.y;
            acc[6] += xs[j] * wc.z; acc[7] += xs[j] * wc.w;
        }
    }
#pragma unroll
    for (int e = 0; e < NE; e++)
#pragma unroll
        for (int s = 32; s > 0; s >>= 1)
            acc[e] += __shfl_down(acc[e], s, 64);
    if (lane == 0) {
        float lg[NE], p[NE];
        float mx = -1e30f;
#pragma unroll
        for (int e = 0; e < NE; e++) { lg[e] = acc[e] + gb[e]; mx = fmaxf(mx, lg[e]); }
        float s = 0.f;
#pragma unroll
        for (int e = 0; e < NE; e++) { p[e] = __expf(lg[e] - mx); s += p[e]; }
        const float inv = 1.f / s;
#pragma unroll
        for (int e = 0; e < NE; e++) p[e] *= inv;
        int i0 = 0; float p0 = p[0];
#pragma unroll
        for (int e = 1; e < NE; e++) if (p[e] > p0) { p0 = p[e]; i0 = e; }
        int i1 = -1; float p1 = -1.f;
#pragma unroll
        for (int e = 0; e < NE; e++) if (e != i0 && p[e] > p1) { p1 = p[e]; i1 = e; }
        top_idx[tokn * 2] = i0;  top_idx[tokn * 2 + 1] = i1;
        top_gate[tokn * 2] = p0; top_gate[tokn * 2 + 1] = p1;
    }
}

// LDS histogram -> 8 global atomics per block (16 blocks => 128 total).
__global__ void count_kernel(const int* __restrict__ top_idx, int* __restrict__ cnt) {
    __shared__ int hist[NE];
    if (threadIdx.x < NE) hist[threadIdx.x] = 0;
    __syncthreads();
    const int n = blockIdx.x * 256 + threadIdx.x;
    atomicAdd(&hist[top_idx[n * 2]], 1);
    atomicAdd(&hist[top_idx[n * 2 + 1]], 1);
    __syncthreads();
    if (threadIdx.x < NE) atomicAdd(&cnt[threadIdx.x], hist[threadIdx.x]);
}

// Row assignment: inline 8-wide prefix scan + LDS ranks + 8 global atomics/block.
__global__ void build_kernel(const int* __restrict__ top_idx, const int* __restrict__ cnt,
                             int* __restrict__ run, int* __restrict__ row_token,
                             int* __restrict__ tok_row) {
    __shared__ int soffs[NE];
    __shared__ int lrun[NE];
    __shared__ int base[NE];
    if (threadIdx.x == 0) {
        int s = 0;
        for (int e = 0; e < NE; e++) { soffs[e] = s; s += cnt[e]; }
    }
    if (threadIdx.x < NE) lrun[threadIdx.x] = 0;
    __syncthreads();
    const int n = blockIdx.x * 256 + threadIdx.x;
    const int e0 = top_idx[n * 2], e1 = top_idx[n * 2 + 1];
    const int p0 = atomicAdd(&lrun[e0], 1);
    const int p1 = atomicAdd(&lrun[e1], 1);
    __syncthreads();
    if (threadIdx.x < NE) base[threadIdx.x] = atomicAdd(&run[threadIdx.x], lrun[threadIdx.x]);
    __syncthreads();
    const int r0 = soffs[e0] + base[e0] + p0;
    const int r1 = soffs[e1] + base[e1] + p1;
    row_token[r0] = n; tok_row[n * 2] = r0;
    row_token[r1] = n; tok_row[n * 2 + 1] = r1;
}

// ---------------------------------------------------------------------------
// Grouped GEMM1: h[r] = relu(x[tok(r)] @ W1t[e] + b1[e]), bf16 out.
// 128x256 tile, BK=64, global_load_lds(16B), XOR-swizzled LDS (R5-verified
// pattern: row=128B, chunk q of row r at slot q^(r&7)).
// XCD-aware packed grid: lin = e + 8*t, t in [0,256): n0t=t&7 (fast),
// mt=t>>3 (slow) => active blocks packed at low lin per XCD; xcd ~= e.
// ---------------------------------------------------------------------------
__global__ __launch_bounds__(256, 2) void gemm1_kernel(
    const __bf16* __restrict__ xb, const __bf16* __restrict__ w1t,
    const float* __restrict__ b1, const int* __restrict__ cnt,
    const int* __restrict__ row_token, __bf16* __restrict__ h) {
    const int lin = blockIdx.x;
    const int e   = lin & 7;
    const int t   = lin >> 3;
    const int n0  = (t & 7) * 256;
    const int mt  = t >> 3;
    int off_e = 0;
    for (int i = 0; i < e; i++) off_e += cnt[i];
    const int ce = cnt[e];
    if (mt * 128 >= ce) return;

    __shared__ __bf16 lA[8192];    // 128 rows x 64 = 16 KB
    __shared__ __bf16 lB[16384];   // 256 rows x 64 = 32 KB

    const int tid  = threadIdx.x;
    const int lane = tid & 63;
    const int wid  = tid >> 6;
    const int quad = lane >> 4;
    const int l16  = lane & 15;
    const int wm   = wid & 1;
    const int wn   = wid >> 1;

    // staging: group g covers rows g*8..g*8+7; lane -> (lrow, cch) [R5 pattern]
    const int lrow = lane >> 3;              // row within 8-row group
    const int cch  = (lane & 7) ^ lrow;      // global 16B-chunk within row
    const __bf16* aros[4]; char* ldsA[4];    // A: 16 groups / 4 waves
#pragma unroll
    for (int j = 0; j < 4; j++) {
        const int g   = wid * 4 + j;
        const int row = g * 8 + lrow;                 // 0..127
        int gr = off_e + mt * 128 + row;
        gr = gr < 2 * N_TOK - 1 ? gr : 2 * N_TOK - 1;
        const int tok = row_token[gr] & (N_TOK - 1);
        aros[j] = xb + (size_t)tok * DIM + cch * 8;
        ldsA[j] = (char*)lA + g * 1024;
    }
    const __bf16* bros[8]; char* ldsB[8];    // B: 32 groups / 4 waves
#pragma unroll
    for (int j = 0; j < 8; j++) {
        const int g   = wid * 8 + j;
        const int row = g * 8 + lrow;                 // 0..255
        bros[j] = w1t + ((size_t)e * HID + n0 + row) * DIM + cch * 8;
        ldsB[j] = (char*)lB + g * 1024;
    }

    f32x4 acc[4][8] = {};

    for (int kk = 0; kk < DIM; kk += 64) {
#pragma unroll
        for (int j = 0; j < 4; j++) gload16(aros[j] + kk, ldsA[j]);
#pragma unroll
        for (int j = 0; j < 8; j++) gload16(bros[j] + kk, ldsB[j]);
        __syncthreads();
#pragma unroll
        for (int hh = 0; hh < 2; hh++) {
            const int sw = (((hh * 4 + quad) ^ (l16 & 7)) << 4);
            bf16x8 af[4], bfr[8];
#pragma unroll
            for (int mi = 0; mi < 4; mi++)
                af[mi] = *(const bf16x8*)((const char*)lA + (wm * 64 + mi * 16 + l16) * 128 + sw);
#pragma unroll
            for (int ni = 0; ni < 8; ni++)
                bfr[ni] = *(const bf16x8*)((const char*)lB + (wn * 128 + ni * 16 + l16) * 128 + sw);
#pragma unroll
            for (int mi = 0; mi < 4; mi++)
#pragma unroll
                for (int ni = 0; ni < 8; ni++)
                    acc[mi][ni] = __builtin_amdgcn_mfma_f32_16x16x32_bf16(af[mi], bfr[ni], acc[mi][ni], 0, 0, 0);
        }
        __syncthreads();
    }

#pragma unroll
    for (int ni = 0; ni < 8; ni++) {
        const int col = n0 + wn * 128 + ni * 16 + l16;
        const float bias = b1[e * HID + col];
#pragma unroll
        for (int mi = 0; mi < 4; mi++) {
#pragma unroll
            for (int r = 0; r < 4; r++) {
                const int lr = wm * 64 + mi * 16 + quad * 4 + r;
                const int gm = mt * 128 + lr;
                if (gm < ce) {
                    float v = acc[mi][ni][r] + bias;
                    v = v > 0.f ? v : 0.f;
                    h[(size_t)(off_e + gm) * HID + col] = (__bf16)v;
                }
            }
        }
    }
}

// ---------------------------------------------------------------------------
// Grouped GEMM2: y[r] = h[r] @ W2t[e] + b2[e], fp32 out. R5 128x128 structure,
// packed decode (n0t fast, mt slow).
// ---------------------------------------------------------------------------
__global__ __launch_bounds__(256, 2) void gemm2_kernel(
    const __bf16* __restrict__ h, const __bf16* __restrict__ w2t,
    const float* __restrict__ b2, const int* __restrict__ cnt,
    float* __restrict__ y) {
    const int lin = blockIdx.x;
    const int e   = lin & 7;
    const int t   = lin >> 3;
    const int n0  = (t & 7) * 128;
    const int mt  = t >> 3;
    int off_e = 0;
    for (int i = 0; i < e; i++) off_e += cnt[i];
    const int ce = cnt[e];
    if (mt * 128 >= ce) return;

    __shared__ __bf16 lA[8192];
    __shared__ __bf16 lB[8192];

    const int tid  = threadIdx.x;
    const int lane = tid & 63;
    const int wid  = tid >> 6;
    const int quad = lane >> 4;
    const int l16  = lane & 15;
    const int wm   = wid & 1;
    const int wn   = wid >> 1;

    const int lrow = lane >> 3;
    const int cch  = (lane & 7) ^ lrow;
    const __bf16* aros[4]; const __bf16* bros[4];
    char* ldsA[4]; char* ldsB[4];
#pragma unroll
    for (int j = 0; j < 4; j++) {
        const int row = (wid * 4 + j) * 8 + lrow;
        int gr = off_e + mt * 128 + row;
        gr = gr < 2 * N_TOK - 1 ? gr : 2 * N_TOK - 1;   // clamp inside h buffer
        aros[j] = h   + (size_t)gr * HID + cch * 8;
        bros[j] = w2t + ((size_t)e * DIM + n0 + row) * HID + cch * 8;
        ldsA[j] = (char*)lA + (wid * 4 + j) * 1024;
        ldsB[j] = (char*)lB + (wid * 4 + j) * 1024;
    }

    f32x4 acc[4][4] = {};

    for (int kk = 0; kk < HID; kk += 64) {
#pragma unroll
        for (int j = 0; j < 4; j++) gload16(aros[j] + kk, ldsA[j]);
#pragma unroll
        for (int j = 0; j < 4; j++) gload16(bros[j] + kk, ldsB[j]);
        __syncthreads();
#pragma unroll
        for (int hh = 0; hh < 2; hh++) {
            const int sw = (((hh * 4 + quad) ^ (l16 & 7)) << 4);
            bf16x8 af[4], bfr[4];
#pragma unroll
            for (int mi = 0; mi < 4; mi++)
                af[mi] = *(const bf16x8*)((const char*)lA + (wm * 64 + mi * 16 + l16) * 128 + sw);
#pragma unroll
            for (int ni = 0; ni < 4; ni++)
                bfr[ni] = *(const bf16x8*)((const char*)lB + (wn * 64 + ni * 16 + l16) * 128 + sw);
#pragma unroll
            for (int mi = 0; mi < 4; mi++)
#pragma unroll
                for (int ni = 0; ni < 4; ni++)
                    acc[mi][ni] = __builtin_amdgcn_mfma_f32_16x16x32_bf16(af[mi], bfr[ni], acc[mi][ni], 0, 0, 0);
        }
        __syncthreads();
    }

#pragma unroll
    for (int mi = 0; mi < 4; mi++) {
#pragma unroll
        for (int r = 0; r < 4; r++) {
            const int lr = wm * 64 + mi * 16 + quad * 4 + r;
            const int gm = mt * 128 + lr;
            if (gm < ce) {
#pragma unroll
                for (int ni = 0; ni < 4; ni++) {
                    const int col = n0 + wn * 64 + ni * 16 + l16;
                    y[(size_t)(off_e + gm) * DIM + col] = acc[mi][ni][r] + b2[e * DIM + col];
                }
            }
        }
    }
}

// out[n] = g0*y[r0] + g1*y[r1] — coalesced, one block per token row.
__global__ void combine_kernel(const float* __restrict__ y, const int* __restrict__ tok_row,
                               const float* __restrict__ top_gate, float* __restrict__ out) {
    const int n = blockIdx.x;
    const int d = threadIdx.x * 4;
    const int r0 = tok_row[n * 2], r1 = tok_row[n * 2 + 1];
    const float g0 = top_gate[n * 2], g1 = top_gate[n * 2 + 1];
    float4 a = *(const float4*)&y[(size_t)r0 * DIM + d];
    float4 b = *(const float4*)&y[(size_t)r1 * DIM + d];
    float4 o = { g0 * a.x + g1 * b.x, g0 * a.y + g1 * b.y,
                 g0 * a.z + g1 * b.z, g0 * a.w + g1 * b.w };
    *(float4*)&out[(size_t)n * DIM + d] = o;
}

// ---------------------------------------------------------------------------
extern "C" void kernel_launch(void* const* d_in, const int* in_sizes, int n_in,
                              void* d_out, int out_size, void* d_ws, size_t ws_size,
                              hipStream_t stream) {
    const float* x  = (const float*)d_in[0];
    const float* gW = (const float*)d_in[1];
    const float* gb = (const float*)d_in[2];
    const float* W1 = (const float*)d_in[3];
    const float* b1 = (const float*)d_in[4];
    const float* W2 = (const float*)d_in[5];
    const float* b2 = (const float*)d_in[6];
    float* out = (float*)d_out;

    char* ws = (char*)d_ws;
    // ws layout:
    //   [0, 8 MiB)    xb  : x bf16 [N][D]
    //   [8, 40 MiB)   w1t : W1^T bf16 [E][H][D]   (dead after gemm1)
    //   [8, 40 MiB)   y   : fp32 [2N][D]          (overlays w1t)
    //   [40, 72 MiB)  w2t : W2^T bf16 [E][D][H]
    //   [72, 104 MiB) h   : bf16 [2N][H]
    //   [104 MiB..)   routing metadata
    __bf16* xb   = (__bf16*)(ws);
    __bf16* w1t  = (__bf16*)(ws + ((size_t)8  << 20));
    float*  ybuf = (float*) (ws + ((size_t)8  << 20));
    __bf16* w2t  = (__bf16*)(ws + ((size_t)40 << 20));
    __bf16* hbuf = (__bf16*)(ws + ((size_t)72 << 20));
    char* tail   = ws + ((size_t)104 << 20);
    int*   row_token = (int*)(tail);
    int*   tok_row   = (int*)(tail + 32768);
    int*   top_idx   = (int*)(tail + 65536);
    float* top_gate  = (float*)(tail + 98304);
    int*   cnt       = (int*)(tail + 131072);
    int*   run       = cnt + 32;

    hipMemsetAsync(cnt, 0, 256, stream);

    gate_kernel<<<N_TOK / 4, 256, 0, stream>>>(x, gW, gb, top_idx, top_gate, xb);
    count_kernel<<<N_TOK / 256, 256, 0, stream>>>(top_idx, cnt);
    build_kernel<<<N_TOK / 256, 256, 0, stream>>>(top_idx, cnt, run, row_token, tok_row);
    transpose_cvt_all<<<32768, 256, 0, stream>>>(W1, W2, w1t, w2t);
    // XCD-aware packed grids: lin = e + 8*t, n0t fast / mt slow
    gemm1_kernel<<<NE * 32 * (HID / 256), 256, 0, stream>>>(xb, w1t, b1, cnt, row_token, hbuf);
    gemm2_kernel<<<NE * 32 * (DIM / 128), 256, 0, stream>>>(hbuf, w2t, b2, cnt, ybuf);
    combine_kernel<<<N_TOK, 256, 0, stream>>>(ybuf, tok_row, top_gate, out);
}